// Round 9
// baseline (202.234 us; speedup 1.0000x reference)
//
#include <hip/hip_runtime.h>

typedef unsigned int uint32;
typedef unsigned long long uint64;
typedef unsigned short ushort_t;
typedef _Float16 h2_t __attribute__((ext_vector_type(2)));
typedef float  f32x2 __attribute__((ext_vector_type(2)));
typedef float  f32x4 __attribute__((ext_vector_type(4)));
typedef uint32 u32x4 __attribute__((ext_vector_type(4)));

#define KNEI 32
#define DIM 128
#define WPB 2              // waves per block (keep LDS/block at 32 KB -> 5 blocks/CU)
#define CH  4              // rows per wave
#define TILE_BYTES 8192    // one 32x128 packed-16b tile
#define WAVE_LDS (2 * TILE_BYTES)

enum { SRC_BF16 = 0, SRC_F16 = 1, SRC_F32 = 2 };

__device__ __forceinline__ float bflo(uint32 u) {
    union { uint32 u; float f; } c; c.u = u << 16; return c.f;
}
__device__ __forceinline__ float bfhi(uint32 u) {
    union { uint32 u; float f; } c; c.u = u & 0xffff0000u; return c.f;
}
__device__ __forceinline__ uint32 pack_bf16_rne(float a, float b) {
    union { float f; uint32 u; } x, y; x.f = a; y.f = b;
    uint32 ua = (x.u + 0x7fffu + ((x.u >> 16) & 1u)) >> 16;
    uint32 ub = (y.u + 0x7fffu + ((y.u >> 16) & 1u)) >> 16;
    return (ua & 0xffffu) | (ub << 16);
}
__device__ __forceinline__ uint32 pack_f16(float a, float b) {
    union { h2_t h; uint32 u; } c;
    c.h.x = (_Float16)a; c.h.y = (_Float16)b;
    return c.u;
}
__device__ __forceinline__ h2_t as_h2(uint32 u) {
    union { uint32 u; h2_t h; } c; c.u = u; return c.h;
}

// async global->LDS, 16B per lane; lds dest = uniform base + lane*16. (verified R7)
__device__ __forceinline__ void prefetch16(const void* g, void* l) {
    __builtin_amdgcn_global_load_lds(
        (const __attribute__((address_space(1))) void*)g,
        (__attribute__((address_space(3))) void*)l,
        16, 0, 0);
}

// counted waits: tile-i's 8 glls are older than the newest-8 ops at the wait.
__device__ __forceinline__ void wait_vm8() {
    asm volatile("s_waitcnt vmcnt(8)" ::: "memory");
    __builtin_amdgcn_sched_barrier(0);
}
__device__ __forceinline__ void wait_vm0() {
    asm volatile("s_waitcnt vmcnt(0)" ::: "memory");
    __builtin_amdgcn_sched_barrier(0);
}

// h: bf16 iff bits 14..7 of every sampled dword look like a bf16 exponent.
__device__ __forceinline__ bool probe_bf16(const void* h, int lane) {
    const uint32 hs = ((const uint32*)h)[lane];
    const uint32 e  = (hs >> 7) & 0xFFu;
    const bool  tb  = (e >= 90u) && (e <= 140u);
    return (__ballot(tb) == ~0ull);
}

// 8-elem dot of one packed-16b quad against an[8].
template<int SRC>
__device__ __forceinline__ float dot8(const uint4 e, const float* an) {
    if constexpr (SRC == SRC_BF16) {
        return bflo(e.x) * an[0] + bfhi(e.x) * an[1]
             + bflo(e.y) * an[2] + bfhi(e.y) * an[3]
             + bflo(e.z) * an[4] + bfhi(e.z) * an[5]
             + bflo(e.w) * an[6] + bfhi(e.w) * an[7];
    } else {
        const h2_t e0 = as_h2(e.x), e1 = as_h2(e.y), e2 = as_h2(e.z), e3 = as_h2(e.w);
        const float t0 = fmaf((float)e0.x, an[0],
                         fmaf((float)e0.y, an[1],
                         fmaf((float)e1.x, an[2], (float)e1.y * an[3])));
        const float t1 = fmaf((float)e2.x, an[4],
                         fmaf((float)e2.y, an[5],
                         fmaf((float)e3.x, an[6], (float)e3.y * an[7])));
        return t0 + t1;
    }
}

// acc[0..7] += wk * e (packed 16-bit quad).
template<int SRC>
__device__ __forceinline__ void acc8(float* acc, float wk, const uint4 e) {
    if constexpr (SRC == SRC_BF16) {
        acc[0] = fmaf(wk, bflo(e.x), acc[0]);
        acc[1] = fmaf(wk, bfhi(e.x), acc[1]);
        acc[2] = fmaf(wk, bflo(e.y), acc[2]);
        acc[3] = fmaf(wk, bfhi(e.y), acc[3]);
        acc[4] = fmaf(wk, bflo(e.z), acc[4]);
        acc[5] = fmaf(wk, bfhi(e.z), acc[5]);
        acc[6] = fmaf(wk, bflo(e.w), acc[6]);
        acc[7] = fmaf(wk, bfhi(e.w), acc[7]);
    } else {
        const h2_t e0 = as_h2(e.x), e1 = as_h2(e.y), e2 = as_h2(e.z), e3 = as_h2(e.w);
        acc[0] = fmaf(wk, (float)e0.x, acc[0]);
        acc[1] = fmaf(wk, (float)e0.y, acc[1]);
        acc[2] = fmaf(wk, (float)e1.x, acc[2]);
        acc[3] = fmaf(wk, (float)e1.y, acc[3]);
        acc[4] = fmaf(wk, (float)e2.x, acc[4]);
        acc[5] = fmaf(wk, (float)e2.y, acc[5]);
        acc[6] = fmaf(wk, (float)e3.x, acc[6]);
        acc[7] = fmaf(wk, (float)e3.y, acc[7]);
    }
}

// Score + softmax + weighted-sum for ONE row (tile in ev[8]); returns this
// lane's 2 output dims [8c + 2*r4, +2) via reduce-scatter. (verified R6/R7)
template<int SRC>
__device__ __forceinline__ f32x2 process_row(
    const uint4* ev, const float* an, float base, int r4)
{
    float s[8];
    #pragma unroll
    for (int it = 0; it < 8; ++it) s[it] = dot8<SRC>(ev[it], an);
    #pragma unroll
    for (int off = 1; off <= 8; off <<= 1) {
        #pragma unroll
        for (int it = 0; it < 8; ++it)
            s[it] += __shfl_xor(s[it], off, 64);
    }
    #pragma unroll
    for (int it = 0; it < 8; ++it) {
        const float v = base + s[it];
        s[it] = (v > 0.f) ? v : 0.01f * v;     // leaky_relu
    }

    float m = fmaxf(fmaxf(fmaxf(s[0], s[1]), fmaxf(s[2], s[3])),
                    fmaxf(fmaxf(s[4], s[5]), fmaxf(s[6], s[7])));
    m = fmaxf(m, __shfl_xor(m, 16, 64));
    m = fmaxf(m, __shfl_xor(m, 32, 64));

    float w[8];
    #pragma unroll
    for (int it = 0; it < 8; ++it) w[it] = __expf(s[it] - m);
    float sum = ((w[0] + w[1]) + (w[2] + w[3])) + ((w[4] + w[5]) + (w[6] + w[7]));
    sum += __shfl_xor(sum, 16, 64);
    sum += __shfl_xor(sum, 32, 64);
    const float inv = 1.0f / sum;

    float acc[8] = {0.f, 0.f, 0.f, 0.f, 0.f, 0.f, 0.f, 0.f};
    #pragma unroll
    for (int it = 0; it < 8; ++it)
        acc8<SRC>(acc, w[it] * inv, ev[it]);

    const bool b1 = (r4 & 2) != 0;
    const bool b0 = (r4 & 1) != 0;
    float t[4];
    #pragma unroll
    for (int j = 0; j < 4; ++j) {
        const float keep = b1 ? acc[4 + j] : acc[j];
        const float send = b1 ? acc[j]     : acc[4 + j];
        t[j] = keep + __shfl_xor(send, 32, 64);
    }
    f32x2 o;
    {
        const float k0 = b0 ? t[2] : t[0];
        const float s0 = b0 ? t[0] : t[2];
        o.x = k0 + __shfl_xor(s0, 16, 64);
        const float k1 = b0 ? t[3] : t[1];
        const float s1 = b0 ? t[1] : t[3];
        o.y = k1 + __shfl_xor(s1, 16, 64);
    }
    return o;
}

// Issue the 8 fire-and-forget glls for one tile; rows come from idx register
// (half = 0: lanes 0..31 of idxreg; half = 1: lanes 32..63).
template<int HALF>
__device__ __forceinline__ void stage_tile(const void* __restrict__ hsv,
                                           int idxreg, int r4, int c, char* buf) {
    #pragma unroll
    for (int it = 0; it < 8; ++it) {
        const int row = __shfl(idxreg, HALF * 32 + it * 4 + r4, 64);
        prefetch16((const uint4*)hsv + ((size_t)row << 4) + c, buf + it * 1024);
    }
}

// CH=4 rows per wave. Tiles stream global->LDS (no VGPR backing, unsinkable);
// double-buffered: fetch(i+1) rides under compute(i). No barriers (wave-private LDS).
template<int SRC>   // SRC_BF16 or SRC_F16 (16-bit gather source)
__device__ __forceinline__ void run_chunk_lds(
    const void* __restrict__ hsv, const void* __restrict__ hrv,
    const void* __restrict__ attv, void* __restrict__ outv,
    const void* __restrict__ neiv, bool i64, int Mrows,
    size_t n0, int N, int lane, char* wbase)
{
    constexpr bool F32 = (SRC != SRC_BF16);   // h_refer/att/out are f32
    const int r4 = lane >> 4;
    const int c  = lane & 15;
    const size_t nlast = (size_t)(N - 1);

    // ---- idx loads: two coalesced 64-lane loads cover 4 rows ----
    const size_t rA = (n0 + (size_t)(lane >> 5)     <= nlast) ? n0 + (lane >> 5)     : nlast;
    const size_t rB = (n0 + 2 + (size_t)(lane >> 5) <= nlast) ? n0 + 2 + (lane >> 5) : nlast;
    int idx01, idx23;
    if (i64) {
        idx01 = (int)__builtin_nontemporal_load((const long long*)neiv + rA * KNEI + (lane & 31));
        idx23 = (int)__builtin_nontemporal_load((const long long*)neiv + rB * KNEI + (lane & 31));
    } else {
        idx01 = __builtin_nontemporal_load((const int*)neiv + rA * KNEI + (lane & 31));
        idx23 = __builtin_nontemporal_load((const int*)neiv + rB * KNEI + (lane & 31));
    }
    idx01 = min(max(idx01, 0), Mrows - 1);     // OOB armor
    idx23 = min(max(idx23, 0), Mrows - 1);

    // ---- start the pipeline immediately: tiles 0 and 1 ----
    stage_tile<0>(hsv, idx01, r4, c, wbase);
    stage_tile<1>(hsv, idx01, r4, c, wbase + TILE_BYTES);

    // ---- base scores for 4 rows (16-lane group g -> row n0+g, lane j dims [8j,8j+8)) ----
    const int g = lane >> 4, j = lane & 15;
    const size_t brow = (n0 + (size_t)g <= nlast) ? n0 + g : nlast;
    float bsum;
    if (F32) {
        const f32x4* hp = (const f32x4*)((const float*)hrv + brow * DIM + j * 8);
        const f32x4* ap = (const f32x4*)((const float*)attv + j * 8);
        const f32x4 h0 = __builtin_nontemporal_load(hp);
        const f32x4 h1 = __builtin_nontemporal_load(hp + 1);
        const f32x4 a0 = ap[0], a1 = ap[1];
        bsum = h0.x * a0.x + h0.y * a0.y + h0.z * a0.z + h0.w * a0.w
             + h1.x * a1.x + h1.y * a1.y + h1.z * a1.z + h1.w * a1.w;
    } else {
        const u32x4 hu = __builtin_nontemporal_load(
            (const u32x4*)((const ushort_t*)hrv + brow * DIM + j * 8));
        const u32x4 au = *(const u32x4*)((const ushort_t*)attv + j * 8);
        bsum = bflo(hu.x) * bflo(au.x) + bfhi(hu.x) * bfhi(au.x)
             + bflo(hu.y) * bflo(au.y) + bfhi(hu.y) * bfhi(au.y)
             + bflo(hu.z) * bflo(au.z) + bfhi(hu.z) * bfhi(au.z)
             + bflo(hu.w) * bflo(au.w) + bfhi(hu.w) * bfhi(au.w);
    }
    #pragma unroll
    for (int off = 1; off <= 8; off <<= 1)
        bsum += __shfl_xor(bsum, off, 64);
    float base[CH];
    #pragma unroll
    for (int i = 0; i < CH; ++i)
        base[i] = __shfl(bsum, i << 4, 64);

    // ---- att_nei chunk for dims [8c, 8c+8) ----
    float an[8];
    if (F32) {
        const float4* ap = (const float4*)((const float*)attv + DIM + c * 8);
        const float4 p0 = ap[0], p1 = ap[1];
        an[0] = p0.x; an[1] = p0.y; an[2] = p0.z; an[3] = p0.w;
        an[4] = p1.x; an[5] = p1.y; an[6] = p1.z; an[7] = p1.w;
    } else {
        const uint4 au = *((const uint4*)((const ushort_t*)attv + DIM) + c);
        an[0] = bflo(au.x); an[1] = bfhi(au.x); an[2] = bflo(au.y); an[3] = bfhi(au.y);
        an[4] = bflo(au.z); an[5] = bfhi(au.z); an[6] = bflo(au.w); an[7] = bfhi(au.w);
    }

    f32x2 o[CH];
    uint4 ev[8];
    const int lb = lane * 16;

    // ---- iter 0: wait tile0 (tile1 stays in flight), compute, refill buf0 ----
    wait_vm8();
    #pragma unroll
    for (int it = 0; it < 8; ++it) ev[it] = *(const uint4*)(wbase + it * 1024 + lb);
    o[0] = process_row<SRC>(ev, an, base[0], r4);
    __builtin_amdgcn_sched_barrier(0);
    stage_tile<0>(hsv, idx23, r4, c, wbase);            // tile2 -> buf0

    // ---- iter 1 ----
    wait_vm8();
    #pragma unroll
    for (int it = 0; it < 8; ++it) ev[it] = *(const uint4*)(wbase + TILE_BYTES + it * 1024 + lb);
    o[1] = process_row<SRC>(ev, an, base[1], r4);
    __builtin_amdgcn_sched_barrier(0);
    stage_tile<1>(hsv, idx23, r4, c, wbase + TILE_BYTES); // tile3 -> buf1

    // ---- iter 2 ----
    wait_vm8();
    #pragma unroll
    for (int it = 0; it < 8; ++it) ev[it] = *(const uint4*)(wbase + it * 1024 + lb);
    o[2] = process_row<SRC>(ev, an, base[2], r4);

    // ---- iter 3 (drain) ----
    wait_vm0();
    #pragma unroll
    for (int it = 0; it < 8; ++it) ev[it] = *(const uint4*)(wbase + TILE_BYTES + it * 1024 + lb);
    o[3] = process_row<SRC>(ev, an, base[3], r4);

    // ---- deferred coalesced NT stores ----
    const int soff = c * 4 + r4;
    #pragma unroll
    for (int i = 0; i < CH; ++i) {
        if (n0 + (size_t)i <= nlast) {
            if (F32) {
                __builtin_nontemporal_store(o[i],
                    (f32x2*)((float*)outv + (n0 + i) * DIM) + soff);
            } else {
                __builtin_nontemporal_store(pack_bf16_rne(o[i].x, o[i].y),
                    (uint32*)((ushort_t*)outv + (n0 + i) * DIM) + soff);
            }
        }
    }
}

// f32 fallback (no workspace): correctness-only register path.
__device__ __forceinline__ void run_chunk_f32(
    const void* __restrict__ hsv, const void* __restrict__ hrv,
    const void* __restrict__ attv, void* __restrict__ outv,
    const void* __restrict__ neiv, bool i64, int Mrows,
    size_t n0, int N, int lane)
{
    const int r4 = lane >> 4;
    const int c  = lane & 15;
    const size_t nlast = (size_t)(N - 1);

    float an[8];
    {
        const float4* ap = (const float4*)((const float*)attv + DIM + c * 8);
        const float4 p0 = ap[0], p1 = ap[1];
        an[0] = p0.x; an[1] = p0.y; an[2] = p0.z; an[3] = p0.w;
        an[4] = p1.x; an[5] = p1.y; an[6] = p1.z; an[7] = p1.w;
    }

    for (int i = 0; i < CH; ++i) {
        const size_t n = (n0 + (size_t)i <= nlast) ? n0 + i : nlast;
        int idxv;
        if (i64) idxv = (int)((const long long*)neiv)[n * KNEI + (lane & 31)];
        else     idxv = ((const int*)neiv)[n * KNEI + (lane & 31)];
        idxv = min(max(idxv, 0), Mrows - 1);

        uint4 ev[8];
        #pragma unroll
        for (int it = 0; it < 8; ++it) {
            const int row = __shfl(idxv, it * 4 + r4, 64);
            const float4* sp = (const float4*)hsv + ((size_t)row << 5) + c * 2;
            const float4 p0 = sp[0], p1 = sp[1];
            ev[it].x = pack_f16(p0.x, p0.y);
            ev[it].y = pack_f16(p0.z, p0.w);
            ev[it].z = pack_f16(p1.x, p1.y);
            ev[it].w = pack_f16(p1.z, p1.w);
        }

        float bsum;
        {
            const f32x4 hp = *((const f32x4*)((const float*)hrv + n * DIM) + (lane & 31));
            const f32x4 ap2 = *((const f32x4*)attv + (lane & 31));
            bsum = hp.x * ap2.x + hp.y * ap2.y + hp.z * ap2.z + hp.w * ap2.w;
        }
        #pragma unroll
        for (int off = 1; off <= 16; off <<= 1)
            bsum += __shfl_xor(bsum, off, 64);
        const float base = __shfl(bsum, 0, 64);

        const f32x2 o = process_row<SRC_F32>(ev, an, base, r4);
        if (n0 + (size_t)i <= nlast) {
            f32x2 ov; ov.x = o.x; ov.y = o.y;
            *((f32x2*)((float*)outv + n * DIM) + c * 4 + r4) = ov;
        }
    }
}

__global__ __launch_bounds__(64 * WPB) void gat_kernel(
    const void* __restrict__ nei, const void* __restrict__ h,
    const void* __restrict__ h_refer, const void* __restrict__ att,
    void* __restrict__ out, const void* __restrict__ hf16,
    int N, int Mrows, int use_ws)
{
    __shared__ __align__(16) char smem[WPB * WAVE_LDS];
    const int tid  = threadIdx.x;
    const int lane = tid & 63;
    const int wave = tid >> 6;
    const size_t n0 = ((size_t)blockIdx.x * WPB + wave) * CH;

    // dtype probes (wave-uniform)
    const bool is_bf16 = probe_bf16(h, lane);
    const uint32 nhi = ((const uint32*)nei)[2 * lane + 1];
    const bool  i64  = (__ballot(nhi == 0u) == ~0ull);

    if (n0 >= (size_t)N) return;   // whole wave exits; no barriers anywhere
    char* wbase = smem + wave * WAVE_LDS;   // wave-private LDS region

    if (is_bf16)     run_chunk_lds<SRC_BF16>(h,    h_refer, att, out, nei, i64, Mrows, n0, N, lane, wbase);
    else if (use_ws) run_chunk_lds<SRC_F16 >(hf16, h_refer, att, out, nei, i64, Mrows, n0, N, lane, wbase);
    else             run_chunk_f32(h, h_refer, att, out, nei, i64, Mrows, n0, N, lane);
}

// h (f32) -> fp16 rows in workspace. Early-out if h is already bf16.
__global__ __launch_bounds__(256) void conv_kernel(
    const void* __restrict__ h, uint4* __restrict__ ws, long long ngroups)
{
    if (probe_bf16(h, threadIdx.x & 63)) return;
    const long long i = (long long)blockIdx.x * 256 + threadIdx.x;
    if (i >= ngroups) return;
    const f32x4* sp = (const f32x4*)h + i * 2;
    const f32x4 p0 = __builtin_nontemporal_load(sp);
    const f32x4 p1 = __builtin_nontemporal_load(sp + 1);
    uint4 o;
    o.x = pack_f16(p0.x, p0.y);
    o.y = pack_f16(p0.z, p0.w);
    o.z = pack_f16(p1.x, p1.y);
    o.w = pack_f16(p1.z, p1.w);
    ws[i] = o;
}

extern "C" void kernel_launch(void* const* d_in, const int* in_sizes, int n_in,
                              void* d_out, int out_size, void* d_ws, size_t ws_size,
                              hipStream_t stream) {
    const int N = out_size / DIM;          // authoritative: output rows
    const int M = in_sizes[1] / DIM;       // h rows (element count is dtype-independent)

    const size_t need = (size_t)M * DIM * sizeof(ushort_t);
    const int use_ws = (d_ws != nullptr && ws_size >= need) ? 1 : 0;

    if (use_ws) {
        const long long ngroups = (long long)M * (DIM / 8);   // 8 elems per thread
        dim3 cg((unsigned)((ngroups + 255) / 256)), cb(256);
        conv_kernel<<<cg, cb, 0, stream>>>(d_in[1], (uint4*)d_ws, ngroups);
    }

    const int rows_per_block = WPB * CH;
    dim3 grid((N + rows_per_block - 1) / rows_per_block), block(64 * WPB);
    gat_kernel<<<grid, block, 0, stream>>>(d_in[0], d_in[1], d_in[2], d_in[3],
                                           d_out, d_ws, N, M, use_ws);
}

// Round 10
// 159.391 us; speedup vs baseline: 1.2688x; 1.2688x over previous
//
#include <hip/hip_runtime.h>

typedef unsigned int uint32;
typedef unsigned long long uint64;
typedef unsigned short ushort_t;
typedef _Float16 h2_t __attribute__((ext_vector_type(2)));
typedef float  f32x2 __attribute__((ext_vector_type(2)));
typedef float  f32x4 __attribute__((ext_vector_type(4)));
typedef uint32 u32x2 __attribute__((ext_vector_type(2)));

#define KNEI 32
#define DIM 128
#define WPB 4            // waves per block
#define RPW 2            // rows per wave

enum { SRC_BF16 = 0, SRC_F16 = 1, SRC_F32 = 2 };

__device__ __forceinline__ float bflo(uint32 u) {
    union { uint32 u; float f; } c; c.u = u << 16; return c.f;
}
__device__ __forceinline__ float bfhi(uint32 u) {
    union { uint32 u; float f; } c; c.u = u & 0xffff0000u; return c.f;
}
__device__ __forceinline__ uint32 pack_bf16_rne(float a, float b) {
    union { float f; uint32 u; } x, y; x.f = a; y.f = b;
    uint32 ua = (x.u + 0x7fffu + ((x.u >> 16) & 1u)) >> 16;
    uint32 ub = (y.u + 0x7fffu + ((y.u >> 16) & 1u)) >> 16;
    return (ua & 0xffffu) | (ub << 16);
}
__device__ __forceinline__ uint32 pack_f16(float a, float b) {
    union { h2_t h; uint32 u; } c;
    c.h.x = (_Float16)a; c.h.y = (_Float16)b;
    return c.u;
}
__device__ __forceinline__ h2_t as_h2(uint32 u) {
    union { uint32 u; h2_t h; } c; c.u = u; return c.h;
}

// h: bf16 iff bits 14..7 of every sampled dword look like a bf16 exponent.
__device__ __forceinline__ bool probe_bf16(const void* h, int lane) {
    const uint32 hs = ((const uint32*)h)[lane];
    const uint32 e  = (hs >> 7) & 0xFFu;
    const bool  tb  = (e >= 90u) && (e <= 140u);
    return (__ballot(tb) == ~0ull);
}

// 8-elem dot of one packed-16b quad against an[8].
template<int SRC>
__device__ __forceinline__ float dot8(const uint4 e, const float* an) {
    if constexpr (SRC == SRC_BF16) {
        return bflo(e.x) * an[0] + bfhi(e.x) * an[1]
             + bflo(e.y) * an[2] + bfhi(e.y) * an[3]
             + bflo(e.z) * an[4] + bfhi(e.z) * an[5]
             + bflo(e.w) * an[6] + bfhi(e.w) * an[7];
    } else {
        const h2_t e0 = as_h2(e.x), e1 = as_h2(e.y), e2 = as_h2(e.z), e3 = as_h2(e.w);
        const float t0 = fmaf((float)e0.x, an[0],
                         fmaf((float)e0.y, an[1],
                         fmaf((float)e1.x, an[2], (float)e1.y * an[3])));
        const float t1 = fmaf((float)e2.x, an[4],
                         fmaf((float)e2.y, an[5],
                         fmaf((float)e3.x, an[6], (float)e3.y * an[7])));
        return t0 + t1;
    }
}

// acc[0..7] += wk * e (packed 16-bit quad).
template<int SRC>
__device__ __forceinline__ void acc8(float* acc, float wk, const uint4 e) {
    if constexpr (SRC == SRC_BF16) {
        acc[0] = fmaf(wk, bflo(e.x), acc[0]);
        acc[1] = fmaf(wk, bfhi(e.x), acc[1]);
        acc[2] = fmaf(wk, bflo(e.y), acc[2]);
        acc[3] = fmaf(wk, bfhi(e.y), acc[3]);
        acc[4] = fmaf(wk, bflo(e.z), acc[4]);
        acc[5] = fmaf(wk, bfhi(e.z), acc[5]);
        acc[6] = fmaf(wk, bflo(e.w), acc[6]);
        acc[7] = fmaf(wk, bfhi(e.w), acc[7]);
    } else {
        const h2_t e0 = as_h2(e.x), e1 = as_h2(e.y), e2 = as_h2(e.z), e3 = as_h2(e.w);
        acc[0] = fmaf(wk, (float)e0.x, acc[0]);
        acc[1] = fmaf(wk, (float)e0.y, acc[1]);
        acc[2] = fmaf(wk, (float)e1.x, acc[2]);
        acc[3] = fmaf(wk, (float)e1.y, acc[3]);
        acc[4] = fmaf(wk, (float)e2.x, acc[4]);
        acc[5] = fmaf(wk, (float)e2.y, acc[5]);
        acc[6] = fmaf(wk, (float)e3.x, acc[6]);
        acc[7] = fmaf(wk, (float)e3.y, acc[7]);
    }
}

// Score + softmax + weighted-sum for ONE row (tile in ev[8]); returns this
// lane's 2 output dims [8c + 2*r4, +2) via reduce-scatter epilogue
// (verified correct in R6/R7/R9 passed runs; ~20 fewer ops than butterfly).
template<int SRC>
__device__ __forceinline__ f32x2 process_row(
    const uint4* ev, const float* an, float base, int r4)
{
    float s[8];
    #pragma unroll
    for (int it = 0; it < 8; ++it) s[it] = dot8<SRC>(ev[it], an);
    #pragma unroll
    for (int off = 1; off <= 8; off <<= 1) {
        #pragma unroll
        for (int it = 0; it < 8; ++it)
            s[it] += __shfl_xor(s[it], off, 64);
    }
    #pragma unroll
    for (int it = 0; it < 8; ++it) {
        const float v = base + s[it];
        s[it] = (v > 0.f) ? v : 0.01f * v;     // leaky_relu
    }

    float m = fmaxf(fmaxf(fmaxf(s[0], s[1]), fmaxf(s[2], s[3])),
                    fmaxf(fmaxf(s[4], s[5]), fmaxf(s[6], s[7])));
    m = fmaxf(m, __shfl_xor(m, 16, 64));
    m = fmaxf(m, __shfl_xor(m, 32, 64));

    float w[8];
    #pragma unroll
    for (int it = 0; it < 8; ++it) w[it] = __expf(s[it] - m);
    float sum = ((w[0] + w[1]) + (w[2] + w[3])) + ((w[4] + w[5]) + (w[6] + w[7]));
    sum += __shfl_xor(sum, 16, 64);
    sum += __shfl_xor(sum, 32, 64);
    const float inv = 1.0f / sum;

    float acc[8] = {0.f, 0.f, 0.f, 0.f, 0.f, 0.f, 0.f, 0.f};
    #pragma unroll
    for (int it = 0; it < 8; ++it)
        acc8<SRC>(acc, w[it] * inv, ev[it]);

    // reduce-scatter across r4 groups: lane keeps only its 2 store dims.
    const bool b1 = (r4 & 2) != 0;
    const bool b0 = (r4 & 1) != 0;
    float t[4];
    #pragma unroll
    for (int j = 0; j < 4; ++j) {
        const float keep = b1 ? acc[4 + j] : acc[j];
        const float send = b1 ? acc[j]     : acc[4 + j];
        t[j] = keep + __shfl_xor(send, 32, 64);
    }
    f32x2 o;
    {
        const float k0 = b0 ? t[2] : t[0];
        const float s0 = b0 ? t[0] : t[2];
        o.x = k0 + __shfl_xor(s0, 16, 64);
        const float k1 = b0 ? t[3] : t[1];
        const float s1 = b0 ? t[1] : t[3];
        o.y = k1 + __shfl_xor(s1, 16, 64);
    }
    return o;
}

// Two rows per wave (R3 structure — best verified: 55 us, VGPR 60):
// shared nei load (one coalesced 64-lane load covers both rows), shared
// att/an loads, 16 gathers issued up front, rows processed sequentially.
template<int SRC>
__device__ __forceinline__ void run_two(
    const void* __restrict__ hsv, const void* __restrict__ hrv,
    const void* __restrict__ attv, void* __restrict__ outv,
    const void* __restrict__ neiv, bool i64, int Mrows,
    size_t n0, bool valid2, int lane)
{
    constexpr bool F32 = (SRC != SRC_BF16);
    const int r4 = lane >> 4;
    const int c  = lane & 15;

    // nei indices: lanes 0..31 -> row n0, lanes 32..63 -> row n0+1 (contiguous)
    const size_t ebase = n0 * KNEI;
    const int esel = valid2 ? lane : (lane & 31);   // clamp if row B absent
    int idxv;
    if (i64) idxv = (int)__builtin_nontemporal_load((const long long*)neiv + ebase + esel);
    else     idxv = __builtin_nontemporal_load((const int*)neiv + ebase + esel);
    idxv = min(max(idxv, 0), Mrows - 1);            // OOB armor

    int rows_a[8], rows_b[8];
    #pragma unroll
    for (int it = 0; it < 8; ++it) {
        rows_a[it] = __shfl(idxv, it * 4 + r4, 64);
        rows_b[it] = __shfl(idxv, 32 + it * 4 + r4, 64);
    }

    // issue ALL 16 gather loads before any compute
    uint4 evA[8], evB[8];
    #pragma unroll
    for (int it = 0; it < 8; ++it) {
        if constexpr (SRC == SRC_F32) {
            const float4* sp = (const float4*)hsv + ((size_t)rows_a[it] << 5) + c * 2;
            const float4 p0 = sp[0], p1 = sp[1];
            evA[it].x = pack_f16(p0.x, p0.y);
            evA[it].y = pack_f16(p0.z, p0.w);
            evA[it].z = pack_f16(p1.x, p1.y);
            evA[it].w = pack_f16(p1.z, p1.w);
        } else {
            evA[it] = *((const uint4*)hsv + ((size_t)rows_a[it] << 4) + c);
        }
    }
    #pragma unroll
    for (int it = 0; it < 8; ++it) {
        if constexpr (SRC == SRC_F32) {
            const float4* sp = (const float4*)hsv + ((size_t)rows_b[it] << 5) + c * 2;
            const float4 p0 = sp[0], p1 = sp[1];
            evB[it].x = pack_f16(p0.x, p0.y);
            evB[it].y = pack_f16(p0.z, p0.w);
            evB[it].z = pack_f16(p1.x, p1.y);
            evB[it].w = pack_f16(p1.z, p1.w);
        } else {
            evB[it] = *((const uint4*)hsv + ((size_t)rows_b[it] << 4) + c);
        }
    }

    // base scores for BOTH rows in one pass: half-wave r2 handles row n0+r2,
    // lane covers dims [4*l5, 4*l5+4).
    const int r2 = lane >> 5;
    const int l5 = lane & 31;
    const size_t brow = n0 + (valid2 ? (size_t)r2 : 0);
    float bsum;
    if (F32) {
        const f32x4 hp = __builtin_nontemporal_load(
            (const f32x4*)((const float*)hrv + brow * DIM) + l5);
        const f32x4 ap = *((const f32x4*)attv + l5);
        bsum = hp.x * ap.x + hp.y * ap.y + hp.z * ap.z + hp.w * ap.w;
    } else {
        const u32x2 hu = __builtin_nontemporal_load(
            (const u32x2*)((const ushort_t*)hrv + brow * DIM) + l5);
        const u32x2 au = *((const u32x2*)attv + l5);
        bsum = bflo(hu.x) * bflo(au.x) + bfhi(hu.x) * bfhi(au.x)
             + bflo(hu.y) * bflo(au.y) + bfhi(hu.y) * bfhi(au.y);
    }
    #pragma unroll
    for (int off = 1; off <= 16; off <<= 1)
        bsum += __shfl_xor(bsum, off, 64);
    const float baseA = __shfl(bsum, 0, 64);
    const float baseB = __shfl(bsum, 32, 64);

    // att_nei chunk for dims [8c, 8c+8) — shared by both rows
    float an[8];
    if (F32) {
        const float4* ap = (const float4*)((const float*)attv + DIM + c * 8);
        const float4 p0 = ap[0], p1 = ap[1];
        an[0] = p0.x; an[1] = p0.y; an[2] = p0.z; an[3] = p0.w;
        an[4] = p1.x; an[5] = p1.y; an[6] = p1.z; an[7] = p1.w;
    } else {
        const uint4 au = *((const uint4*)((const ushort_t*)attv + DIM) + c);
        an[0] = bflo(au.x); an[1] = bfhi(au.x); an[2] = bflo(au.y); an[3] = bfhi(au.y);
        an[4] = bflo(au.z); an[5] = bfhi(au.z); an[6] = bflo(au.w); an[7] = bfhi(au.w);
    }

    // rows processed sequentially (R3 equilibrium; ILP attempts all regressed)
    const f32x2 oA = process_row<SRC>(evA, an, baseA, r4);
    const f32x2 oB = process_row<SRC>(evB, an, baseB, r4);

    // lane stores dims [8c + 2*r4, +2): fully coalesced, non-temporal
    const int soff = c * 4 + r4;
    if (F32) {
        __builtin_nontemporal_store(oA, (f32x2*)((float*)outv + n0 * DIM) + soff);
        if (valid2)
            __builtin_nontemporal_store(oB, (f32x2*)((float*)outv + (n0 + 1) * DIM) + soff);
    } else {
        __builtin_nontemporal_store(pack_bf16_rne(oA.x, oA.y),
            (uint32*)((ushort_t*)outv + n0 * DIM) + soff);
        if (valid2)
            __builtin_nontemporal_store(pack_bf16_rne(oB.x, oB.y),
                (uint32*)((ushort_t*)outv + (n0 + 1) * DIM) + soff);
    }
}

__global__ __launch_bounds__(256) void gat_kernel(
    const void* __restrict__ nei, const void* __restrict__ h,
    const void* __restrict__ h_refer, const void* __restrict__ att,
    void* __restrict__ out, const void* __restrict__ hf16,
    int N, int Mrows, int use_ws)
{
    const int tid  = threadIdx.x;
    const int lane = tid & 63;
    const size_t n0 = ((size_t)blockIdx.x * WPB + (tid >> 6)) * RPW;

    // dtype probes (wave-uniform)
    const bool is_bf16 = probe_bf16(h, lane);
    const uint32 nhi = ((const uint32*)nei)[2 * lane + 1];
    const bool  i64  = (__ballot(nhi == 0u) == ~0ull);

    if (n0 >= (size_t)N) return;   // whole wave exits together; no barriers anywhere
    const bool valid2 = (n0 + 1 < (size_t)N);

    if (is_bf16)     run_two<SRC_BF16>(h,    h_refer, att, out, nei, i64, Mrows, n0, valid2, lane);
    else if (use_ws) run_two<SRC_F16 >(hf16, h_refer, att, out, nei, i64, Mrows, n0, valid2, lane);
    else             run_two<SRC_F32 >(h,    h_refer, att, out, nei, i64, Mrows, n0, valid2, lane);
}

// h (f32) -> fp16 rows in workspace. Early-out if h is already bf16.
__global__ __launch_bounds__(256) void conv_kernel(
    const void* __restrict__ h, uint4* __restrict__ ws, long long ngroups)
{
    if (probe_bf16(h, threadIdx.x & 63)) return;
    const long long i = (long long)blockIdx.x * 256 + threadIdx.x;
    if (i >= ngroups) return;
    const f32x4* sp = (const f32x4*)h + i * 2;
    const f32x4 p0 = __builtin_nontemporal_load(sp);
    const f32x4 p1 = __builtin_nontemporal_load(sp + 1);
    uint4 o;
    o.x = pack_f16(p0.x, p0.y);
    o.y = pack_f16(p0.z, p0.w);
    o.z = pack_f16(p1.x, p1.y);
    o.w = pack_f16(p1.z, p1.w);
    ws[i] = o;
}

extern "C" void kernel_launch(void* const* d_in, const int* in_sizes, int n_in,
                              void* d_out, int out_size, void* d_ws, size_t ws_size,
                              hipStream_t stream) {
    const int N = out_size / DIM;          // authoritative: output rows
    const int M = in_sizes[1] / DIM;       // h rows (element count is dtype-independent)

    const size_t need = (size_t)M * DIM * sizeof(ushort_t);
    const int use_ws = (d_ws != nullptr && ws_size >= need) ? 1 : 0;

    if (use_ws) {
        const long long ngroups = (long long)M * (DIM / 8);   // 8 elems per thread
        dim3 cg((unsigned)((ngroups + 255) / 256)), cb(256);
        conv_kernel<<<cg, cb, 0, stream>>>(d_in[1], (uint4*)d_ws, ngroups);
    }

    const int rows_per_block = WPB * RPW;
    dim3 grid((N + rows_per_block - 1) / rows_per_block), block(64 * WPB);
    gat_kernel<<<grid, block, 0, stream>>>(d_in[0], d_in[1], d_in[2], d_in[3],
                                           d_out, d_ws, N, M, use_ws);
}

// Round 11
// 146.890 us; speedup vs baseline: 1.3768x; 1.0851x over previous
//
#include <hip/hip_runtime.h>

typedef unsigned int uint32;
typedef unsigned long long uint64;
typedef unsigned short ushort_t;
typedef _Float16 h2_t __attribute__((ext_vector_type(2)));
typedef float  f32x2 __attribute__((ext_vector_type(2)));
typedef float  f32x4 __attribute__((ext_vector_type(4)));
typedef uint32 u32x2 __attribute__((ext_vector_type(2)));

#define KNEI 32
#define DIM 128
#define WPB 4            // waves per block
#define RPW 2            // rows per wave

enum { SRC_BF16 = 0, SRC_F16 = 1, SRC_F32 = 2 };

__device__ __forceinline__ float bflo(uint32 u) {
    union { uint32 u; float f; } c; c.u = u << 16; return c.f;
}
__device__ __forceinline__ float bfhi(uint32 u) {
    union { uint32 u; float f; } c; c.u = u & 0xffff0000u; return c.f;
}
__device__ __forceinline__ uint32 pack_bf16_rne(float a, float b) {
    union { float f; uint32 u; } x, y; x.f = a; y.f = b;
    uint32 ua = (x.u + 0x7fffu + ((x.u >> 16) & 1u)) >> 16;
    uint32 ub = (y.u + 0x7fffu + ((y.u >> 16) & 1u)) >> 16;
    return (ua & 0xffffu) | (ub << 16);
}
__device__ __forceinline__ uint32 pack_f16(float a, float b) {
    union { h2_t h; uint32 u; } c;
    c.h.x = (_Float16)a; c.h.y = (_Float16)b;
    return c.u;
}
__device__ __forceinline__ h2_t as_h2(uint32 u) {
    union { uint32 u; h2_t h; } c; c.u = u; return c.h;
}

// h: bf16 iff bits 14..7 of every sampled dword look like a bf16 exponent.
__device__ __forceinline__ bool probe_bf16(const void* h, int lane) {
    const uint32 hs = ((const uint32*)h)[lane];
    const uint32 e  = (hs >> 7) & 0xFFu;
    const bool  tb  = (e >= 90u) && (e <= 140u);
    return (__ballot(tb) == ~0ull);
}

// Score + softmax + weighted-sum + store for ONE row whose 32x128 tile (packed
// 16-bit) lives in ev[8] spread over all 64 lanes (lane = 16*r4 + c owns
// neighbor k = 4*it + r4, dims [8c, 8c+8)).   [R3 golden epilogue: butterfly]
template<int SRC>
__device__ __forceinline__ void process_row(
    const uint4* ev, const float* an, float base,
    void* __restrict__ outv, size_t n, int lane, int r4, int c)
{
    constexpr bool F32 = (SRC != SRC_BF16);

    // score partials s[it] = dot(row[8c..8c+8), att_nei[8c..8c+8))
    float s[8];
    #pragma unroll
    for (int it = 0; it < 8; ++it) {
        const uint4 e = ev[it];
        if constexpr (SRC == SRC_BF16) {
            s[it] = bflo(e.x) * an[0] + bfhi(e.x) * an[1]
                  + bflo(e.y) * an[2] + bfhi(e.y) * an[3]
                  + bflo(e.z) * an[4] + bfhi(e.z) * an[5]
                  + bflo(e.w) * an[6] + bfhi(e.w) * an[7];
        } else {
            const h2_t e0 = as_h2(e.x), e1 = as_h2(e.y), e2 = as_h2(e.z), e3 = as_h2(e.w);
            const float t0 = fmaf((float)e0.x, an[0],
                             fmaf((float)e0.y, an[1],
                             fmaf((float)e1.x, an[2], (float)e1.y * an[3])));
            const float t1 = fmaf((float)e2.x, an[4],
                             fmaf((float)e2.y, an[5],
                             fmaf((float)e3.x, an[6], (float)e3.y * an[7])));
            s[it] = t0 + t1;
        }
    }
    // reduce over c (bits 0..3): every lane in a 16-group gets its k's full dot
    #pragma unroll
    for (int off = 1; off <= 8; off <<= 1) {
        #pragma unroll
        for (int it = 0; it < 8; ++it)
            s[it] += __shfl_xor(s[it], off, 64);
    }
    #pragma unroll
    for (int it = 0; it < 8; ++it) {
        const float v = base + s[it];
        s[it] = (v > 0.f) ? v : 0.01f * v;     // leaky_relu
    }

    // softmax over 32 neighbors: local over it, then across r4 groups (bits 4,5)
    float m = s[0];
    #pragma unroll
    for (int it = 1; it < 8; ++it) m = fmaxf(m, s[it]);
    m = fmaxf(m, __shfl_xor(m, 16, 64));
    m = fmaxf(m, __shfl_xor(m, 32, 64));

    float w[8];
    float sum = 0.f;
    #pragma unroll
    for (int it = 0; it < 8; ++it) { w[it] = __expf(s[it] - m); sum += w[it]; }
    sum += __shfl_xor(sum, 16, 64);
    sum += __shfl_xor(sum, 32, 64);
    const float inv = 1.0f / sum;

    // weighted accumulation (weights already on the owning lane)
    float acc[8] = {0.f, 0.f, 0.f, 0.f, 0.f, 0.f, 0.f, 0.f};
    #pragma unroll
    for (int it = 0; it < 8; ++it) {
        const float wk = w[it] * inv;
        const uint4 e = ev[it];
        if constexpr (SRC == SRC_BF16) {
            acc[0] = fmaf(wk, bflo(e.x), acc[0]);
            acc[1] = fmaf(wk, bfhi(e.x), acc[1]);
            acc[2] = fmaf(wk, bflo(e.y), acc[2]);
            acc[3] = fmaf(wk, bfhi(e.y), acc[3]);
            acc[4] = fmaf(wk, bflo(e.z), acc[4]);
            acc[5] = fmaf(wk, bfhi(e.z), acc[5]);
            acc[6] = fmaf(wk, bflo(e.w), acc[6]);
            acc[7] = fmaf(wk, bfhi(e.w), acc[7]);
        } else {
            const h2_t e0 = as_h2(e.x), e1 = as_h2(e.y), e2 = as_h2(e.z), e3 = as_h2(e.w);
            acc[0] = fmaf(wk, (float)e0.x, acc[0]);
            acc[1] = fmaf(wk, (float)e0.y, acc[1]);
            acc[2] = fmaf(wk, (float)e1.x, acc[2]);
            acc[3] = fmaf(wk, (float)e1.y, acc[3]);
            acc[4] = fmaf(wk, (float)e2.x, acc[4]);
            acc[5] = fmaf(wk, (float)e2.y, acc[5]);
            acc[6] = fmaf(wk, (float)e3.x, acc[6]);
            acc[7] = fmaf(wk, (float)e3.y, acc[7]);
        }
    }
    #pragma unroll
    for (int d = 0; d < 8; ++d) acc[d] += __shfl_xor(acc[d], 16, 64);
    #pragma unroll
    for (int d = 0; d < 8; ++d) acc[d] += __shfl_xor(acc[d], 32, 64);

    // lane stores dims [8c + 2*r4, +2): fully coalesced; NT (never re-read)
    const float q0a = (r4 & 2) ? acc[4] : acc[0];
    const float q0b = (r4 & 2) ? acc[5] : acc[1];
    const float q1a = (r4 & 2) ? acc[6] : acc[2];
    const float q1b = (r4 & 2) ? acc[7] : acc[3];
    const float o0 = (r4 & 1) ? q1a : q0a;
    const float o1 = (r4 & 1) ? q1b : q0b;

    if (F32) {
        f32x2 o; o.x = o0; o.y = o1;
        __builtin_nontemporal_store(o, (f32x2*)((float*)outv + n * DIM) + c * 4 + r4);
    } else {
        __builtin_nontemporal_store(pack_bf16_rne(o0, o1),
            (uint32*)((ushort_t*)outv + n * DIM) + c * 4 + r4);
    }
}

// Two rows per wave: shared nei load (one coalesced 64-lane load covers both
// rows), shared att/an loads, 16 gather loads issued up front.   [R3 golden]
template<int SRC>
__device__ __forceinline__ void run_two(
    const void* __restrict__ hsv, const void* __restrict__ hrv,
    const void* __restrict__ attv, void* __restrict__ outv,
    const void* __restrict__ neiv, bool i64, int Mrows,
    int n0, bool valid2, int lane)
{
    constexpr bool F32 = (SRC != SRC_BF16);
    const int r4 = lane >> 4;
    const int c  = lane & 15;

    // nei indices: lanes 0..31 -> row n0, lanes 32..63 -> row n0+1 (contiguous)
    const size_t ebase = (size_t)n0 * KNEI;
    const int esel = valid2 ? lane : (lane & 31);   // clamp if row B absent
    int idxv;
    if (i64) idxv = (int)__builtin_nontemporal_load((const long long*)neiv + ebase + esel);
    else     idxv = __builtin_nontemporal_load((const int*)neiv + ebase + esel);
    idxv = min(max(idxv, 0), Mrows - 1);            // OOB armor

    int rows_a[8], rows_b[8];
    #pragma unroll
    for (int it = 0; it < 8; ++it) {
        rows_a[it] = __shfl(idxv, it * 4 + r4, 64);
        rows_b[it] = __shfl(idxv, 32 + it * 4 + r4, 64);
    }

    // issue ALL 16 gather loads before any compute
    uint4 eva[8], evb[8];
    #pragma unroll
    for (int it = 0; it < 8; ++it) {
        if constexpr (SRC == SRC_F32) {
            const float4* sp = (const float4*)hsv + ((size_t)rows_a[it] << 5) + c * 2;
            const float4 p0 = sp[0], p1 = sp[1];
            eva[it].x = pack_f16(p0.x, p0.y);
            eva[it].y = pack_f16(p0.z, p0.w);
            eva[it].z = pack_f16(p1.x, p1.y);
            eva[it].w = pack_f16(p1.z, p1.w);
        } else {
            eva[it] = *((const uint4*)hsv + ((size_t)rows_a[it] << 4) + c);
        }
    }
    #pragma unroll
    for (int it = 0; it < 8; ++it) {
        if constexpr (SRC == SRC_F32) {
            const float4* sp = (const float4*)hsv + ((size_t)rows_b[it] << 5) + c * 2;
            const float4 p0 = sp[0], p1 = sp[1];
            evb[it].x = pack_f16(p0.x, p0.y);
            evb[it].y = pack_f16(p0.z, p0.w);
            evb[it].z = pack_f16(p1.x, p1.y);
            evb[it].w = pack_f16(p1.z, p1.w);
        } else {
            evb[it] = *((const uint4*)hsv + ((size_t)rows_b[it] << 4) + c);
        }
    }

    // base scores for BOTH rows in one pass: half-wave r2 handles row n0+r2,
    // lane covers dims [4*l5, 4*l5+4).
    const int r2 = lane >> 5;
    const int l5 = lane & 31;
    const size_t brow = (size_t)n0 + (valid2 ? r2 : 0);
    float bsum;
    if (F32) {
        const f32x4 hp = __builtin_nontemporal_load(
            (const f32x4*)((const float*)hrv + brow * DIM) + l5);
        const f32x4 ap = *((const f32x4*)attv + l5);
        bsum = hp.x * ap.x + hp.y * ap.y + hp.z * ap.z + hp.w * ap.w;
    } else {
        const u32x2 hu = __builtin_nontemporal_load(
            (const u32x2*)((const ushort_t*)hrv + brow * DIM) + l5);
        const u32x2 au = *((const u32x2*)attv + l5);
        bsum = bflo(hu.x) * bflo(au.x) + bfhi(hu.x) * bfhi(au.x)
             + bflo(hu.y) * bflo(au.y) + bfhi(hu.y) * bfhi(au.y);
    }
    #pragma unroll
    for (int off = 1; off <= 16; off <<= 1)
        bsum += __shfl_xor(bsum, off, 64);
    const float baseA = __shfl(bsum, 0, 64);
    const float baseB = __shfl(bsum, 32, 64);

    // att_nei chunk for dims [8c, 8c+8) — shared by both rows
    float an[8];
    if (F32) {
        const float4* ap = (const float4*)((const float*)attv + DIM + c * 8);
        const float4 p0 = ap[0], p1 = ap[1];
        an[0] = p0.x; an[1] = p0.y; an[2] = p0.z; an[3] = p0.w;
        an[4] = p1.x; an[5] = p1.y; an[6] = p1.z; an[7] = p1.w;
    } else {
        const uint4 au = *((const uint4*)((const ushort_t*)attv + DIM) + c);
        an[0] = bflo(au.x); an[1] = bfhi(au.x); an[2] = bflo(au.y); an[3] = bfhi(au.y);
        an[4] = bflo(au.z); an[5] = bfhi(au.z); an[6] = bflo(au.w); an[7] = bfhi(au.w);
    }

    process_row<SRC>(eva, an, baseA, outv, (size_t)n0, lane, r4, c);
    if (valid2)
        process_row<SRC>(evb, an, baseB, outv, (size_t)n0 + 1, lane, r4, c);
}

__global__ __launch_bounds__(256) void gat_kernel(
    const void* __restrict__ nei, const void* __restrict__ h,
    const void* __restrict__ h_refer, const void* __restrict__ att,
    void* __restrict__ out, const void* __restrict__ hf16,
    int N, int Mrows, int use_ws)
{
    const int tid  = threadIdx.x;
    const int lane = tid & 63;
    const int n0   = (blockIdx.x * WPB + (tid >> 6)) * RPW;

    // dtype probes (wave-uniform)
    const bool is_bf16 = probe_bf16(h, lane);
    const uint32 nhi = ((const uint32*)nei)[2 * lane + 1];
    const bool  i64  = (__ballot(nhi == 0u) == ~0ull);

    if (n0 >= N) return;   // whole wave exits together; no barriers anywhere
    const bool valid2 = (n0 + 1 < N);

    if (is_bf16)     run_two<SRC_BF16>(h,    h_refer, att, out, nei, i64, Mrows, n0, valid2, lane);
    else if (use_ws) run_two<SRC_F16 >(hf16, h_refer, att, out, nei, i64, Mrows, n0, valid2, lane);
    else             run_two<SRC_F32 >(h,    h_refer, att, out, nei, i64, Mrows, n0, valid2, lane);
}

// h (f32) -> fp16 rows in workspace. Early-out if h is already bf16.
__global__ __launch_bounds__(256) void conv_kernel(
    const void* __restrict__ h, uint4* __restrict__ ws, long long ngroups)
{
    if (probe_bf16(h, threadIdx.x & 63)) return;
    const long long i = (long long)blockIdx.x * 256 + threadIdx.x;
    if (i >= ngroups) return;
    const f32x4* sp = (const f32x4*)h + i * 2;
    const f32x4 p0 = __builtin_nontemporal_load(sp);
    const f32x4 p1 = __builtin_nontemporal_load(sp + 1);
    uint4 o;
    o.x = pack_f16(p0.x, p0.y);
    o.y = pack_f16(p0.z, p0.w);
    o.z = pack_f16(p1.x, p1.y);
    o.w = pack_f16(p1.z, p1.w);
    ws[i] = o;
}

extern "C" void kernel_launch(void* const* d_in, const int* in_sizes, int n_in,
                              void* d_out, int out_size, void* d_ws, size_t ws_size,
                              hipStream_t stream) {
    const int N = out_size / DIM;          // authoritative: output rows
    const int M = in_sizes[1] / DIM;       // h rows (element count is dtype-independent)

    const size_t need = (size_t)M * DIM * sizeof(ushort_t);
    const int use_ws = (d_ws != nullptr && ws_size >= need) ? 1 : 0;

    if (use_ws) {
        const long long ngroups = (long long)M * (DIM / 8);   // 8 elems per thread
        dim3 cg((unsigned)((ngroups + 255) / 256)), cb(256);
        conv_kernel<<<cg, cb, 0, stream>>>(d_in[1], (uint4*)d_ws, ngroups);
    }

    const int rows_per_block = WPB * RPW;
    dim3 grid((N + rows_per_block - 1) / rows_per_block), block(64 * WPB);
    gat_kernel<<<grid, block, 0, stream>>>(d_in[0], d_in[1], d_in[2], d_in[3],
                                           d_out, d_ws, N, M, use_ws);
}